// Round 4
// baseline (442.414 us; speedup 1.0000x reference)
//
#include <hip/hip_runtime.h>
#include <hip/hip_bf16.h>
#include <math.h>

// Problem constants (B=2,S=1024 -> T=2048; D=1024; H=4096; E=8; top-2)
// ALL inputs/outputs are FLOAT32. We convert x/W1/W2/Ws1/Ws2 to bf16 in the
// workspace for MFMA; biases and gating stay f32.
#define NTOK 2048
#define DDIM 1024
#define HDIM 4096
#define NEXP 8
#define NROWS (3 * NTOK)  // 2*NTOK routed + NTOK shared rows in grouped space
#define KSPLIT2 2         // split-K factor for GEMM2

typedef __bf16 bf16x8 __attribute__((ext_vector_type(8)));
typedef float f32x4 __attribute__((ext_vector_type(4)));
typedef __attribute__((address_space(1))) char as1_char;
typedef __attribute__((address_space(3))) char as3_char;

__device__ __forceinline__ void async16(const void* g, void* l) {
  // async global->LDS, 16B/lane; LDS dest = wave-uniform base + lane*16
  __builtin_amdgcn_global_load_lds((as1_char*)g, (as3_char*)l, 16, 0, 0);
}

// Branch-free erf (Abramowitz-Stegun 7.1.26, |err|<=1.5e-7) -> exact-form gelu.
__device__ __forceinline__ float gelu_fast(float v) {
  const float x = v * 0.70710678118654752f;
  const float ax = fabsf(x);
  const float t = __builtin_amdgcn_rcpf(1.0f + 0.3275911f * ax);
  float p = 1.061405429f;
  p = p * t - 1.453152027f;
  p = p * t + 1.421413741f;
  p = p * t - 0.284496736f;
  p = p * t + 0.254829592f;
  const float y = 1.0f - p * t * __expf(-ax * ax);
  const float erfv = copysignf(y, x);
  return 0.5f * v * (1.0f + erfv);
}

// ---------------------------------------------------------------------------
// f32 -> bf16 conversion, 8 elems/thread, 16B vector store. n % 2048 == 0.
// ---------------------------------------------------------------------------
__global__ void __launch_bounds__(256) cvt_bf16(const float* __restrict__ in,
                                                __hip_bfloat16* __restrict__ out) {
  const size_t i = ((size_t)blockIdx.x * 256 + threadIdx.x) * 8;
  const float4 a = *(const float4*)(in + i);
  const float4 b = *(const float4*)(in + i + 4);
  union { __hip_bfloat16 h[8]; uint4 u; } p;
  p.h[0] = __float2bfloat16(a.x); p.h[1] = __float2bfloat16(a.y);
  p.h[2] = __float2bfloat16(a.z); p.h[3] = __float2bfloat16(a.w);
  p.h[4] = __float2bfloat16(b.x); p.h[5] = __float2bfloat16(b.y);
  p.h[6] = __float2bfloat16(b.z); p.h[7] = __float2bfloat16(b.w);
  *(uint4*)(out + i) = p.u;
}

__global__ void moe_zero_out(float* __restrict__ a) {
  a[(size_t)blockIdx.x * 256 + threadIdx.x] = 0.f;
}
__global__ void moe_zero_misc(int* counts) {
  if (threadIdx.x < NEXP) counts[threadIdx.x] = 0;
}

// ---------------------------------------------------------------------------
// Core 128(M) x 256(N) tile GEMM, 4 waves, per-wave 128x64 output (round-8).
// Rounds 1-3 post-mortem: gemm time (~145us) was invariant under conflicts->0,
// prefetch depth 1->2, and tile 128^2 -> 256^2 because the limit is the LDS
// PIPE: per-wave 64x64 tiles read 8KB LDS per 16 MFMA = 32 FLOP/LDS-byte ->
// 1.6GB reads + 0.6GB DMA-writes per GEMM / ~85-110 B/cyc/CU = the measured
// 130-150us. Fix: raise FLOP per LDS-byte with a 128x64 per-wave tile
// (8x4 frags of 16x16x32, acc=128 VGPR): (8 A + 4 B) b128 reads per 32 MFMA
// = 43.7 FLOP/B. Block = 4 waves side-by-side in N (BM=128 shared A, BN=256).
//   - LDS/buf: A [128 x 64B] 8KB + B [256 x 64B] 16KB = 24KB; 2 bufs = 48KB
//     -> 2 blocks/CU (VGPR ~210 caps 2 waves/SIMD).
//   - BK=32 (64B rows): keeps the round-2-verified bank-free XOR swizzle:
//     store chunk (l&3)^((l>>3)&3) of row l>>2 (linear LDS dest, permuted
//     global source within the same 64B line); read slot quad^((lr>>1)&3).
//   - Staging: 6 DMAs/wave/iter (2 A + 4 B); depth-1 prefetch, counted
//     vmcnt(6) -- never drains the prefetch queue in the main loop.
// Schedule correctness (same skeleton as rounds 0-3): stage(i+1) overwrites
// buf cur^1, whose readers all passed the trailing barrier of iter i-1
// before any wave enters iter i; per-wave vmcnt before the leading barrier
// guarantees own stage(i) DMAs landed; the barrier publishes them.
// ---------------------------------------------------------------------------
__device__ __forceinline__ void gemm_core(const char* const* gA,  // [2] per-thread row ptrs
                                          const char* const* gB,  // [4] per-thread row ptrs
                                          char* sm, int Kbytes, int tid,
                                          f32x4 acc[8][4]) {
  const int w = tid >> 6, l = tid & 63;
  const int lr = l & 15, quad = l >> 4;
  const int swz16 = (quad ^ ((lr >> 1) & 3)) * 16;  // bank-free read slot
  const int niter = Kbytes >> 6;

  auto stage = [&](int it, int buf) {
    char* base = sm + buf * 24576;
    const int kb = it * 64;
    // A: wave w covers rows [w*32, w*32+32): 2 DMAs of 16 rows each.
    async16(gA[0] + kb, base + w * 2048);
    async16(gA[1] + kb, base + w * 2048 + 1024);
    // B: wave w covers rows [w*64, w*64+64): 4 DMAs of 16 rows each.
    async16(gB[0] + kb, base + 8192 + w * 4096);
    async16(gB[1] + kb, base + 8192 + w * 4096 + 1024);
    async16(gB[2] + kb, base + 8192 + w * 4096 + 2048);
    async16(gB[3] + kb, base + 8192 + w * 4096 + 3072);
  };

  stage(0, 0);
  for (int i = 0; i < niter; ++i) {
    const int cur = i & 1;
    if (i + 1 < niter) {
      stage(i + 1, cur ^ 1);                  // 12 DMAs now outstanding (own)
      __builtin_amdgcn_s_waitcnt(0x0F76);     // vmcnt(6): wait stage(i) only
    } else {
      __builtin_amdgcn_s_waitcnt(0x0F70);     // vmcnt(0): last tile
    }
    __builtin_amdgcn_s_barrier();             // raw: no vmcnt(0) drain of prefetch
    const char* rb = sm + cur * 24576;
    bf16x8 av[8], bv[4];
#pragma unroll
    for (int i2 = 0; i2 < 8; ++i2)
      av[i2] = *(const bf16x8*)(rb + (i2 * 16 + lr) * 64 + swz16);
#pragma unroll
    for (int j = 0; j < 4; ++j)
      bv[j] = *(const bf16x8*)(rb + 8192 + (w * 64 + j * 16 + lr) * 64 + swz16);
#pragma unroll
    for (int i2 = 0; i2 < 8; ++i2)
#pragma unroll
      for (int j = 0; j < 4; ++j)
        acc[i2][j] = __builtin_amdgcn_mfma_f32_16x16x32_bf16(av[i2], bv[j], acc[i2][j], 0, 0, 0);
    __builtin_amdgcn_s_barrier();             // all reads of buf[cur] done before
  }                                           // next iter's stage overwrites it
}

// Per-lane staging geometry: lane l stages the 16B chunk ((l&3) ^ ((l>>3)&3))
// of row (l>>2) within each 16-row DMA block -- places chunk c of row r in
// LDS slot c ^ ((r>>1)&3) with a LINEAR LDS destination (same 64B line, no
// coalescing loss). Verified bank-free in round 2 (SQ_LDS_BANK_CONFLICT -> 0).
__device__ __forceinline__ int stage_colb(int l) {
  return (((l & 3) ^ ((l >> 3) & 3)) * 16);
}

// ---------------------------------------------------------------------------
// Gating: one wave per token, all f32. scores = sigmoid(x @ Wg^T + bg + bias);
// top-2 with lax.top_k tie-break (lowest index first). Slot via atomics.
// ---------------------------------------------------------------------------
__global__ void __launch_bounds__(64) moe_gate(
    const float* __restrict__ x, const float* __restrict__ Wg,
    const float* __restrict__ bg, const float* __restrict__ bias,
    int* __restrict__ counts, int* __restrict__ topk_idx,
    float* __restrict__ topk_w, int* __restrict__ slot) {
  const int t = blockIdx.x, lane = threadIdx.x;
  float xv[16];
#pragma unroll
  for (int q = 0; q < 16; ++q) xv[q] = x[(size_t)t * DDIM + q * 64 + lane];
  float sc[NEXP];
#pragma unroll
  for (int e = 0; e < NEXP; ++e) {
    float s = 0.f;
#pragma unroll
    for (int q = 0; q < 16; ++q) s += xv[q] * Wg[(size_t)e * DDIM + q * 64 + lane];
#pragma unroll
    for (int o = 32; o > 0; o >>= 1) s += __shfl_xor(s, o, 64);
    sc[e] = 1.0f / (1.0f + expf(-(s + bg[e] + bias[e])));
  }
  if (lane == 0) {
    int k0 = 0;
    for (int e = 1; e < NEXP; ++e)
      if (sc[e] > sc[k0]) k0 = e;
    int k1 = (k0 == 0) ? 1 : 0;
    for (int e = 0; e < NEXP; ++e) {
      if (e == k0) continue;
      if (sc[e] > sc[k1]) k1 = e;
    }
    topk_idx[t * 2 + 0] = k0;
    topk_idx[t * 2 + 1] = k1;
    topk_w[t * 2 + 0] = sc[k0];
    topk_w[t * 2 + 1] = sc[k1];
    slot[t * 2 + 0] = atomicAdd(&counts[k0], 1);
    slot[t * 2 + 1] = atomicAdd(&counts[k1], 1);
  }
}

__global__ void moe_scan(const int* __restrict__ counts, int* __restrict__ offsets) {
  if (threadIdx.x == 0) {
    int s = 0;
    for (int e = 0; e < NEXP; ++e) { offsets[e] = s; s += counts[e]; }
    offsets[NEXP] = s;  // == 2*NTOK
  }
}

__global__ void moe_scatter(const int* __restrict__ topk_idx, const float* __restrict__ topk_w,
                            const int* __restrict__ slot, const int* __restrict__ offsets,
                            int* __restrict__ row_token, float* __restrict__ row_w) {
  const int t = blockIdx.x * blockDim.x + threadIdx.x;
  if (t >= NTOK) return;
#pragma unroll
  for (int k = 0; k < 2; ++k) {
    const int e = topk_idx[t * 2 + k];
    const int rg = offsets[e] + slot[t * 2 + k];
    row_token[rg] = t;
    row_w[rg] = topk_w[t * 2 + k];
  }
  // shared "expert 8": every token, weight 1.0, rows [2*NTOK, 3*NTOK)
  row_token[2 * NTOK + t] = t;
  row_w[2 * NTOK + t] = 1.0f;
}

// ---------------------------------------------------------------------------
// Grouped GEMM1: h1[row,:] = gelu(xbf[token(row),:] @ W1bf[e]^T + b1[e]) (bf16)
// 128x256 tiles: grid (H/256, NTOK/128, E+1); e==NEXP -> shared expert.
// ---------------------------------------------------------------------------
__global__ void __launch_bounds__(256) moe_gemm1(
    const __hip_bfloat16* __restrict__ xbf, const __hip_bfloat16* __restrict__ W1bf,
    const float* __restrict__ b1, const __hip_bfloat16* __restrict__ Ws1bf,
    const float* __restrict__ bs1, const int* __restrict__ counts,
    const int* __restrict__ offsets, const int* __restrict__ row_token,
    __hip_bfloat16* __restrict__ h1) {
  __shared__ alignas(16) char sm[49152];
  const int e = blockIdx.z, mt = blockIdx.y, nt = blockIdx.x;
  const int cnt = (e < NEXP) ? counts[e] : NTOK;
  if (mt * 128 >= cnt) return;
  const int off = (e < NEXP) ? offsets[e] : 2 * NTOK;
  const __hip_bfloat16* Bw = (e < NEXP) ? (W1bf + (size_t)e * HDIM * DDIM) : Ws1bf;
  const float* bb = (e < NEXP) ? (b1 + e * HDIM) : bs1;

  const int tid = threadIdx.x;
  const int w = tid >> 6, l = tid & 63;
  const int rl = l >> 2;              // staging row within a 16-row DMA block
  const int colb = stage_colb(l);     // swizzled 16B chunk col offset

  // A rows (gathered by token): wave w rows w*32 + q*16 + rl, q = 0,1
  const char* ga[2];
#pragma unroll
  for (int q = 0; q < 2; ++q) {
    const int r0 = mt * 128 + w * 32 + q * 16 + rl;
    const int c0 = (r0 < cnt) ? r0 : (cnt - 1);
    const int t0 = row_token[off + c0];
    ga[q] = (const char*)xbf + (size_t)t0 * (DDIM * 2) + colb;
  }
  // B rows: wave w rows w*64 + q*16 + rl, q = 0..3
  const char* gb[4];
#pragma unroll
  for (int q = 0; q < 4; ++q) {
    const int br = nt * 256 + w * 64 + q * 16 + rl;
    gb[q] = (const char*)Bw + (size_t)br * (DDIM * 2) + colb;
  }

  f32x4 acc[8][4] = {};
  gemm_core(ga, gb, sm, DDIM * 2, tid, acc);

  const int lr = l & 15, quad = l >> 4;
#pragma unroll
  for (int i = 0; i < 8; ++i) {
#pragma unroll
    for (int r = 0; r < 4; ++r) {
      const int rowe = mt * 128 + i * 16 + quad * 4 + r;
      if (rowe >= cnt) continue;  // don't stomp next expert's rows
      const size_t orow = (size_t)(off + rowe) * HDIM;
#pragma unroll
      for (int j = 0; j < 4; ++j) {
        const int h = nt * 256 + w * 64 + j * 16 + lr;
        const float v = acc[i][j][r] + bb[h];
        h1[orow + h] = __float2bfloat16(gelu_fast(v));
      }
    }
  }
}

// ---------------------------------------------------------------------------
// Grouped GEMM2 with split-K: out[token,:] += w(row)*(h1[row,:] @ W2bf[e]^T)
// (+ w*b2[e] from K-chunk 0 only). 128x256 tiles.
// grid x = KSPLIT2 * (D/256); y = m-tiles; z = E+1 groups.
// out is f32, pre-zeroed; f32 atomicAdd accumulates.
// ---------------------------------------------------------------------------
__global__ void __launch_bounds__(256) moe_gemm2(
    const __hip_bfloat16* __restrict__ h1, const __hip_bfloat16* __restrict__ W2bf,
    const float* __restrict__ b2, const __hip_bfloat16* __restrict__ Ws2bf,
    const float* __restrict__ bs2, const int* __restrict__ counts,
    const int* __restrict__ offsets, const int* __restrict__ row_token,
    const float* __restrict__ row_w, float* __restrict__ out) {
  __shared__ alignas(16) char sm[49152];
  const int e = blockIdx.z, mt = blockIdx.y;
  const int nt = blockIdx.x & (DDIM / 256 - 1);
  const int kc = blockIdx.x >> 2;  // K-chunk 0..KSPLIT2-1
  const int cnt = (e < NEXP) ? counts[e] : NTOK;
  if (mt * 128 >= cnt) return;
  const int off = (e < NEXP) ? offsets[e] : 2 * NTOK;
  const __hip_bfloat16* Bw = (e < NEXP) ? (W2bf + (size_t)e * DDIM * HDIM) : Ws2bf;
  const float* bb = (e < NEXP) ? (b2 + e * DDIM) : bs2;

  const int tid = threadIdx.x;
  const int w = tid >> 6, l = tid & 63;
  const int rl = l >> 2;
  const int colb = stage_colb(l);            // swizzled 16B chunk col offset
  const int KB = (HDIM * 2) / KSPLIT2;       // bytes of K per chunk
  const size_t kofs = (size_t)kc * KB;       // byte offset into the K dim

  // A rows contiguous in grouped h1; rows >= cnt read the next group's valid
  // (finite) data and are discarded at the store guard.
  const char* ga[2];
#pragma unroll
  for (int q = 0; q < 2; ++q) {
    const int ar = mt * 128 + w * 32 + q * 16 + rl;
    ga[q] = (const char*)h1 + (size_t)(off + ar) * (HDIM * 2) + kofs + colb;
  }
  const char* gb[4];
#pragma unroll
  for (int q = 0; q < 4; ++q) {
    const int br = nt * 256 + w * 64 + q * 16 + rl;
    gb[q] = (const char*)Bw + (size_t)br * (HDIM * 2) + kofs + colb;
  }

  f32x4 acc[8][4] = {};
  gemm_core(ga, gb, sm, KB, tid, acc);

  const int lr = l & 15, quad = l >> 4;
#pragma unroll
  for (int i = 0; i < 8; ++i) {
#pragma unroll
    for (int r = 0; r < 4; ++r) {
      const int rowe = mt * 128 + i * 16 + quad * 4 + r;
      if (rowe >= cnt) continue;
      const int rg = off + rowe;
      const int tok = row_token[rg];
      const float wt = row_w[rg];
#pragma unroll
      for (int j = 0; j < 4; ++j) {
        const int d = nt * 256 + w * 64 + j * 16 + lr;
        const float base = (kc == 0) ? bb[d] : 0.f;  // bias once per output
        atomicAdd(&out[(size_t)tok * DDIM + d], wt * (acc[i][j][r] + base));
      }
    }
  }
}

// ---------------------------------------------------------------------------
extern "C" void kernel_launch(void* const* d_in, const int* in_sizes, int n_in,
                              void* d_out, int out_size, void* d_ws, size_t ws_size,
                              hipStream_t stream) {
  (void)in_sizes; (void)n_in; (void)out_size; (void)ws_size;
  const float* x    = (const float*)d_in[0];
  const float* Wg   = (const float*)d_in[1];
  const float* bg   = (const float*)d_in[2];
  const float* bias = (const float*)d_in[3];
  const float* W1   = (const float*)d_in[4];
  const float* b1   = (const float*)d_in[5];
  const float* W2   = (const float*)d_in[6];
  const float* b2   = (const float*)d_in[7];
  const float* Ws1  = (const float*)d_in[8];
  const float* bs1  = (const float*)d_in[9];
  const float* Ws2  = (const float*)d_in[10];
  const float* bs2  = (const float*)d_in[11];
  float* out = (float*)d_out;

  // workspace carve-out (~200 MB)
  char* ws = (char*)d_ws;
  size_t cur = 0;
  auto take = [&](size_t b) -> void* {
    void* p = ws + cur;
    cur += (b + 255) & ~(size_t)255;
    return p;
  };
  int* counts    = (int*)take(NEXP * 4);
  int* offsets   = (int*)take((NEXP + 1) * 4);
  int* topk_idx  = (int*)take(NTOK * 2 * 4);
  float* topk_w  = (float*)take(NTOK * 2 * 4);
  int* slot      = (int*)take(NTOK * 2 * 4);
  int* row_token = (int*)take(NROWS * 4);
  float* row_w   = (float*)take(NROWS * 4);
  __hip_bfloat16* xbf   = (__hip_bfloat16*)take((size_t)NTOK * DDIM * 2);        //  4 MB
  __hip_bfloat16* W1bf  = (__hip_bfloat16*)take((size_t)NEXP * HDIM * DDIM * 2); // 67 MB
  __hip_bfloat16* W2bf  = (__hip_bfloat16*)take((size_t)NEXP * DDIM * HDIM * 2); // 67 MB
  __hip_bfloat16* Ws1bf = (__hip_bfloat16*)take((size_t)HDIM * DDIM * 2);        //  8 MB
  __hip_bfloat16* Ws2bf = (__hip_bfloat16*)take((size_t)DDIM * HDIM * 2);        //  8 MB
  __hip_bfloat16* h1    = (__hip_bfloat16*)take((size_t)(NROWS + 64) * HDIM * 2);// 51 MB

  // f32 -> bf16 conversions (all sizes divisible by 2048)
  cvt_bf16<<<(NTOK * DDIM) / 2048, 256, 0, stream>>>(x, xbf);
  cvt_bf16<<<(NEXP * HDIM * DDIM) / 2048, 256, 0, stream>>>(W1, W1bf);
  cvt_bf16<<<(NEXP * DDIM * HDIM) / 2048, 256, 0, stream>>>(W2, W2bf);
  cvt_bf16<<<(HDIM * DDIM) / 2048, 256, 0, stream>>>(Ws1, Ws1bf);
  cvt_bf16<<<(DDIM * HDIM) / 2048, 256, 0, stream>>>(Ws2, Ws2bf);

  moe_zero_misc<<<1, 64, 0, stream>>>(counts);
  moe_zero_out<<<(NTOK * DDIM) / 256, 256, 0, stream>>>(out);
  moe_gate<<<NTOK, 64, 0, stream>>>(x, Wg, bg, bias, counts, topk_idx, topk_w, slot);
  moe_scan<<<1, 1, 0, stream>>>(counts, offsets);
  moe_scatter<<<NTOK / 256, 256, 0, stream>>>(topk_idx, topk_w, slot, offsets, row_token, row_w);

  dim3 g1(HDIM / 256, NTOK / 128, NEXP + 1);  // (16, 16, 9), early-exit past counts
  moe_gemm1<<<g1, 256, 0, stream>>>(xbf, W1bf, b1, Ws1bf, bs1, counts, offsets, row_token, h1);

  dim3 g2(KSPLIT2 * (DDIM / 256), NTOK / 128, NEXP + 1);  // (8, 16, 9), split-K
  moe_gemm2<<<g2, 256, 0, stream>>>(h1, W2bf, b2, Ws2bf, bs2, counts, offsets, row_token, row_w, out);
}

// Round 5
// 414.603 us; speedup vs baseline: 1.0671x; 1.0671x over previous
//
#include <hip/hip_runtime.h>
#include <hip/hip_bf16.h>
#include <math.h>

// Problem constants (B=2,S=1024 -> T=2048; D=1024; H=4096; E=8; top-2)
// ALL inputs/outputs are FLOAT32. We convert x/W1/W2/Ws1/Ws2 to bf16 in the
// workspace for MFMA; biases and gating stay f32.
#define NTOK 2048
#define DDIM 1024
#define HDIM 4096
#define NEXP 8
#define NROWS (3 * NTOK)  // 2*NTOK routed + NTOK shared rows in grouped space
#define KSPLIT2 2         // split-K factor for GEMM2

typedef __bf16 bf16x8 __attribute__((ext_vector_type(8)));
typedef float f32x4 __attribute__((ext_vector_type(4)));
typedef __attribute__((address_space(1))) char as1_char;
typedef __attribute__((address_space(3))) char as3_char;

__device__ __forceinline__ void async16(const void* g, void* l) {
  // async global->LDS, 16B/lane; LDS dest = wave-uniform base + lane*16
  __builtin_amdgcn_global_load_lds((as1_char*)g, (as3_char*)l, 16, 0, 0);
}

// Branch-free erf (Abramowitz-Stegun 7.1.26, |err|<=1.5e-7) -> exact-form gelu.
__device__ __forceinline__ float gelu_fast(float v) {
  const float x = v * 0.70710678118654752f;
  const float ax = fabsf(x);
  const float t = __builtin_amdgcn_rcpf(1.0f + 0.3275911f * ax);
  float p = 1.061405429f;
  p = p * t - 1.453152027f;
  p = p * t + 1.421413741f;
  p = p * t - 0.284496736f;
  p = p * t + 0.254829592f;
  const float y = 1.0f - p * t * __expf(-ax * ax);
  const float erfv = copysignf(y, x);
  return 0.5f * v * (1.0f + erfv);
}

// ---------------------------------------------------------------------------
// f32 -> bf16 conversion, 8 elems/thread, 16B vector store. n % 2048 == 0.
// ---------------------------------------------------------------------------
__global__ void __launch_bounds__(256) cvt_bf16(const float* __restrict__ in,
                                                __hip_bfloat16* __restrict__ out) {
  const size_t i = ((size_t)blockIdx.x * 256 + threadIdx.x) * 8;
  const float4 a = *(const float4*)(in + i);
  const float4 b = *(const float4*)(in + i + 4);
  union { __hip_bfloat16 h[8]; uint4 u; } p;
  p.h[0] = __float2bfloat16(a.x); p.h[1] = __float2bfloat16(a.y);
  p.h[2] = __float2bfloat16(a.z); p.h[3] = __float2bfloat16(a.w);
  p.h[4] = __float2bfloat16(b.x); p.h[5] = __float2bfloat16(b.y);
  p.h[6] = __float2bfloat16(b.z); p.h[7] = __float2bfloat16(b.w);
  *(uint4*)(out + i) = p.u;
}

__global__ void moe_zero_out(float* __restrict__ a) {
  a[(size_t)blockIdx.x * 256 + threadIdx.x] = 0.f;
}
__global__ void moe_zero_misc(int* counts) {
  if (threadIdx.x < NEXP) counts[threadIdx.x] = 0;
}

// ---------------------------------------------------------------------------
// Round-9 core: 256x256 tile, 8-PHASE schedule (learn_hip m201/T3+T4 port).
// Rounds 0-2 sat at the 2-barrier-per-K-step structure ceiling (595 cyc/
// blk-iter, faster than m97's own 703); conflicts->0 / depth-2 / tile shape
// all no-ops. The measured escape is the 8-phase counted-vmcnt schedule.
// Geometry: 512 thr = 8 waves (2M x 4N), per-wave 128x64 = 8x4 frags of
// 16x16x32 bf16 MFMA (acc 128 VGPR). K-tile = 64 elems (128B rows).
// LDS: 2 buf x (A 256x128B = 32KB | B 256x128B = 32KB) = 128KB, 1 block/CU.
// Per K-tile, 4 phases: {ds_read subtile || stage-issue -> barrier ->
// setprio(1) 16 MFMA setprio(0) -> barrier}. B-frags (8 b128) read once in
// phase 0, held in regs. Next K-tile's 8 DMAs issued in phases 0-1, so the
// per-K-tile vmcnt(0) (end of phase 3, before the publish barrier) waits on
// loads issued ~2.5-3.5 phases (~500+ cyc) earlier -- the m97 barrier-drain
// stall amortized over 4 phases and mostly pre-satisfied.
// Swizzle (8 slots/row): store logical chunk c of row r at slot c^(r&7) via
// pre-swizzled GLOBAL source (LDS dest linear, same 128B line -> coalesced);
// read at slot (4s+quad)^(lr&7). Uniform 8 lanes/bank-group = b128 minimum.
// Publish correctness: each wave vmcnt(0)s its OWN DMAs for kt+1 before the
// phase-3 trailing barrier; the barrier publishes all waves' DMAs; kt+1
// phase-0 reads follow it. Overwrite safety: kt+1 DMAs (into buf kt-1's)
// are issued only after kt's phase-0 leading barrier, which all waves reach
// only after their kt-1 reads retired (lgkm-drained before kt-1 ph3 MFMA).
// ---------------------------------------------------------------------------
__device__ __forceinline__ void gemm_core8(const char* const gA[4], const char* const gB[4],
                                           char* sm, int NT, int tid, f32x4 acc[8][4]) {
  const int l = tid & 63, w = tid >> 6;
  const int lr = l & 15, quad = l >> 4;
  const int wm = w >> 2, wn = w & 3;
  const int t16 = tid * 16;
  const int sx = lr & 7;
  const int slot0 = (quad ^ sx) * 16;        // k-slice 0 (k = quad*8)
  const int slot1 = ((4 + quad) ^ sx) * 16;  // k-slice 1 (k = 32 + quad*8)
  const int arow = (wm * 128 + lr) * 128;    // A byte base, frag i adds i*2048
  const int brow = (wn * 64 + lr) * 128;     // B byte base, frag j adds j*2048

  auto stageA = [&](int kt, int buf) {
    char* base = sm + buf * 65536;
    const int kb = kt * 128;
#pragma unroll
    for (int a = 0; a < 4; ++a) async16(gA[a] + kb, base + a * 8192 + t16);
  };
  auto stageB = [&](int kt, int buf) {
    char* base = sm + buf * 65536 + 32768;
    const int kb = kt * 128;
#pragma unroll
    for (int a = 0; a < 4; ++a) async16(gB[a] + kb, base + a * 8192 + t16);
  };

  stageA(0, 0);
  stageB(0, 0);
  __builtin_amdgcn_s_waitcnt(0x0F70);  // vmcnt(0): K-tile 0 landed
  __builtin_amdgcn_s_barrier();        // publish to all waves

  for (int kt = 0; kt < NT; ++kt) {
    const int b = kt & 1;
    const char* rA = sm + b * 65536;
    const char* rB = rA + 32768;
    const bool more = (kt + 1 < NT);
    bf16x8 bv[4][2], av[2][2];

    // -------- phase 0: read ALL B + A frags 0,1; issue next A stage --------
#pragma unroll
    for (int j = 0; j < 4; ++j) {
      bv[j][0] = *(const bf16x8*)(rB + brow + j * 2048 + slot0);
      bv[j][1] = *(const bf16x8*)(rB + brow + j * 2048 + slot1);
    }
#pragma unroll
    for (int ii = 0; ii < 2; ++ii) {
      av[ii][0] = *(const bf16x8*)(rA + arow + ii * 2048 + slot0);
      av[ii][1] = *(const bf16x8*)(rA + arow + ii * 2048 + slot1);
    }
    if (more) stageA(kt + 1, b ^ 1);
    __builtin_amdgcn_s_barrier();
    __builtin_amdgcn_s_setprio(1);
#pragma unroll
    for (int s = 0; s < 2; ++s)
#pragma unroll
      for (int ii = 0; ii < 2; ++ii)
#pragma unroll
        for (int j = 0; j < 4; ++j)
          acc[ii][j] = __builtin_amdgcn_mfma_f32_16x16x32_bf16(av[ii][s], bv[j][s], acc[ii][j], 0, 0, 0);
    __builtin_amdgcn_s_setprio(0);
    __builtin_amdgcn_s_barrier();

    // -------- phase 1: read A frags 2,3; issue next B stage --------
#pragma unroll
    for (int ii = 0; ii < 2; ++ii) {
      av[ii][0] = *(const bf16x8*)(rA + arow + (2 + ii) * 2048 + slot0);
      av[ii][1] = *(const bf16x8*)(rA + arow + (2 + ii) * 2048 + slot1);
    }
    if (more) stageB(kt + 1, b ^ 1);
    __builtin_amdgcn_s_barrier();
    __builtin_amdgcn_s_setprio(1);
#pragma unroll
    for (int s = 0; s < 2; ++s)
#pragma unroll
      for (int ii = 0; ii < 2; ++ii)
#pragma unroll
        for (int j = 0; j < 4; ++j)
          acc[2 + ii][j] = __builtin_amdgcn_mfma_f32_16x16x32_bf16(av[ii][s], bv[j][s], acc[2 + ii][j], 0, 0, 0);
    __builtin_amdgcn_s_setprio(0);
    __builtin_amdgcn_s_barrier();

    // -------- phase 2: read A frags 4,5 --------
#pragma unroll
    for (int ii = 0; ii < 2; ++ii) {
      av[ii][0] = *(const bf16x8*)(rA + arow + (4 + ii) * 2048 + slot0);
      av[ii][1] = *(const bf16x8*)(rA + arow + (4 + ii) * 2048 + slot1);
    }
    __builtin_amdgcn_s_barrier();
    __builtin_amdgcn_s_setprio(1);
#pragma unroll
    for (int s = 0; s < 2; ++s)
#pragma unroll
      for (int ii = 0; ii < 2; ++ii)
#pragma unroll
        for (int j = 0; j < 4; ++j)
          acc[4 + ii][j] = __builtin_amdgcn_mfma_f32_16x16x32_bf16(av[ii][s], bv[j][s], acc[4 + ii][j], 0, 0, 0);
    __builtin_amdgcn_s_setprio(0);
    __builtin_amdgcn_s_barrier();

    // -------- phase 3: read A frags 6,7; per-K-tile publish --------
#pragma unroll
    for (int ii = 0; ii < 2; ++ii) {
      av[ii][0] = *(const bf16x8*)(rA + arow + (6 + ii) * 2048 + slot0);
      av[ii][1] = *(const bf16x8*)(rA + arow + (6 + ii) * 2048 + slot1);
    }
    __builtin_amdgcn_s_barrier();
    __builtin_amdgcn_s_setprio(1);
#pragma unroll
    for (int s = 0; s < 2; ++s)
#pragma unroll
      for (int ii = 0; ii < 2; ++ii)
#pragma unroll
        for (int j = 0; j < 4; ++j)
          acc[6 + ii][j] = __builtin_amdgcn_mfma_f32_16x16x32_bf16(av[ii][s], bv[j][s], acc[6 + ii][j], 0, 0, 0);
    __builtin_amdgcn_s_setprio(0);
    if (more) {
      __builtin_amdgcn_s_waitcnt(0x0F70);  // vmcnt(0): kt+1's 8 DMAs (issued
      __builtin_amdgcn_s_barrier();        // 2.5-3.5 phases ago) -> publish
    }
  }
}

// ---------------------------------------------------------------------------
// Gating: one wave per token, all f32. scores = sigmoid(x @ Wg^T + bg + bias);
// top-2 with lax.top_k tie-break (lowest index first). Slot via atomics.
// ---------------------------------------------------------------------------
__global__ void __launch_bounds__(64) moe_gate(
    const float* __restrict__ x, const float* __restrict__ Wg,
    const float* __restrict__ bg, const float* __restrict__ bias,
    int* __restrict__ counts, int* __restrict__ topk_idx,
    float* __restrict__ topk_w, int* __restrict__ slot) {
  const int t = blockIdx.x, lane = threadIdx.x;
  float xv[16];
#pragma unroll
  for (int q = 0; q < 16; ++q) xv[q] = x[(size_t)t * DDIM + q * 64 + lane];
  float sc[NEXP];
#pragma unroll
  for (int e = 0; e < NEXP; ++e) {
    float s = 0.f;
#pragma unroll
    for (int q = 0; q < 16; ++q) s += xv[q] * Wg[(size_t)e * DDIM + q * 64 + lane];
#pragma unroll
    for (int o = 32; o > 0; o >>= 1) s += __shfl_xor(s, o, 64);
    sc[e] = 1.0f / (1.0f + expf(-(s + bg[e] + bias[e])));
  }
  if (lane == 0) {
    int k0 = 0;
    for (int e = 1; e < NEXP; ++e)
      if (sc[e] > sc[k0]) k0 = e;
    int k1 = (k0 == 0) ? 1 : 0;
    for (int e = 0; e < NEXP; ++e) {
      if (e == k0) continue;
      if (sc[e] > sc[k1]) k1 = e;
    }
    topk_idx[t * 2 + 0] = k0;
    topk_idx[t * 2 + 1] = k1;
    topk_w[t * 2 + 0] = sc[k0];
    topk_w[t * 2 + 1] = sc[k1];
    slot[t * 2 + 0] = atomicAdd(&counts[k0], 1);
    slot[t * 2 + 1] = atomicAdd(&counts[k1], 1);
  }
}

__global__ void moe_scan(const int* __restrict__ counts, int* __restrict__ offsets) {
  if (threadIdx.x == 0) {
    int s = 0;
    for (int e = 0; e < NEXP; ++e) { offsets[e] = s; s += counts[e]; }
    offsets[NEXP] = s;  // == 2*NTOK
  }
}

__global__ void moe_scatter(const int* __restrict__ topk_idx, const float* __restrict__ topk_w,
                            const int* __restrict__ slot, const int* __restrict__ offsets,
                            int* __restrict__ row_token, float* __restrict__ row_w) {
  const int t = blockIdx.x * blockDim.x + threadIdx.x;
  if (t >= NTOK) return;
#pragma unroll
  for (int k = 0; k < 2; ++k) {
    const int e = topk_idx[t * 2 + k];
    const int rg = offsets[e] + slot[t * 2 + k];
    row_token[rg] = t;
    row_w[rg] = topk_w[t * 2 + k];
  }
  // shared "expert 8": every token, weight 1.0, rows [2*NTOK, 3*NTOK)
  row_token[2 * NTOK + t] = t;
  row_w[2 * NTOK + t] = 1.0f;
}

// ---------------------------------------------------------------------------
// Grouped GEMM1: h1[row,:] = gelu(xbf[token(row),:] @ W1bf[e]^T + b1[e]) (bf16)
// 256x256 tiles, 8 waves: grid (H/256, NTOK/256, E+1); e==NEXP -> shared.
// ---------------------------------------------------------------------------
__global__ void __launch_bounds__(512, 2) moe_gemm1(
    const __hip_bfloat16* __restrict__ xbf, const __hip_bfloat16* __restrict__ W1bf,
    const float* __restrict__ b1, const __hip_bfloat16* __restrict__ Ws1bf,
    const float* __restrict__ bs1, const int* __restrict__ counts,
    const int* __restrict__ offsets, const int* __restrict__ row_token,
    __hip_bfloat16* __restrict__ h1) {
  __shared__ alignas(16) char sm[131072];
  const int e = blockIdx.z, mt = blockIdx.y, nt = blockIdx.x;
  const int cnt = (e < NEXP) ? counts[e] : NTOK;
  if (mt * 256 >= cnt) return;
  const int off = (e < NEXP) ? offsets[e] : 2 * NTOK;
  const __hip_bfloat16* Bw = (e < NEXP) ? (W1bf + (size_t)e * HDIM * DDIM) : Ws1bf;
  const float* bb = (e < NEXP) ? (b1 + e * HDIM) : bs1;

  const int tid = threadIdx.x;
  const int rloc = tid >> 3;                       // 0..63 row in 64-row issue
  const int c16 = ((tid & 7) ^ (rloc & 7)) * 16;   // pre-swizzled source chunk

  const char* ga[4];
  const char* gb[4];
#pragma unroll
  for (int a = 0; a < 4; ++a) {
    const int r = mt * 256 + a * 64 + rloc;
    const int cr = (r < cnt) ? r : (cnt - 1);
    const int tok = row_token[off + cr];
    ga[a] = (const char*)xbf + (size_t)tok * (DDIM * 2) + c16;
    gb[a] = (const char*)Bw + (size_t)(nt * 256 + a * 64 + rloc) * (DDIM * 2) + c16;
  }

  f32x4 acc[8][4] = {};
  gemm_core8(ga, gb, sm, (DDIM * 2) / 128, tid, acc);

  const int l = tid & 63, w = tid >> 6;
  const int lr = l & 15, quad = l >> 4;
  const int wm = w >> 2, wn = w & 3;
#pragma unroll
  for (int i = 0; i < 8; ++i) {
#pragma unroll
    for (int r = 0; r < 4; ++r) {
      const int rowe = mt * 256 + wm * 128 + i * 16 + quad * 4 + r;
      if (rowe >= cnt) continue;  // don't stomp next expert's rows
      const size_t orow = (size_t)(off + rowe) * HDIM;
#pragma unroll
      for (int j = 0; j < 4; ++j) {
        const int h = nt * 256 + wn * 64 + j * 16 + lr;
        const float v = acc[i][j][r] + bb[h];
        h1[orow + h] = __float2bfloat16(gelu_fast(v));
      }
    }
  }
}

// ---------------------------------------------------------------------------
// Grouped GEMM2 with split-K: out[token,:] += w(row)*(h1[row,:] @ W2bf[e]^T)
// (+ w*b2[e] from K-chunk 0 only). 256x256 tiles, 8 waves.
// grid x = KSPLIT2 * (D/256); y = m-tiles; z = E+1 groups.
// out is f32, pre-zeroed; f32 atomicAdd accumulates.
// ---------------------------------------------------------------------------
__global__ void __launch_bounds__(512, 2) moe_gemm2(
    const __hip_bfloat16* __restrict__ h1, const __hip_bfloat16* __restrict__ W2bf,
    const float* __restrict__ b2, const __hip_bfloat16* __restrict__ Ws2bf,
    const float* __restrict__ bs2, const int* __restrict__ counts,
    const int* __restrict__ offsets, const int* __restrict__ row_token,
    const float* __restrict__ row_w, float* __restrict__ out) {
  __shared__ alignas(16) char sm[131072];
  const int e = blockIdx.z, mt = blockIdx.y;
  const int nt = blockIdx.x & (DDIM / 256 - 1);
  const int kc = blockIdx.x >> 2;  // K-chunk 0..KSPLIT2-1
  const int cnt = (e < NEXP) ? counts[e] : NTOK;
  if (mt * 256 >= cnt) return;
  const int off = (e < NEXP) ? offsets[e] : 2 * NTOK;
  const __hip_bfloat16* Bw = (e < NEXP) ? (W2bf + (size_t)e * DDIM * HDIM) : Ws2bf;
  const float* bb = (e < NEXP) ? (b2 + e * DDIM) : bs2;

  const int tid = threadIdx.x;
  const int rloc = tid >> 3;
  const int c16 = ((tid & 7) ^ (rloc & 7)) * 16;
  const int KB = (HDIM * 2) / KSPLIT2;   // bytes of K per chunk (4096)
  const size_t kofs = (size_t)kc * KB;

  // A rows contiguous in grouped h1; rows >= cnt read the next group's valid
  // (finite) data and are discarded at the store guard.
  const char* ga[4];
  const char* gb[4];
#pragma unroll
  for (int a = 0; a < 4; ++a) {
    const int ar = mt * 256 + a * 64 + rloc;
    ga[a] = (const char*)h1 + (size_t)(off + ar) * (HDIM * 2) + kofs + c16;
    gb[a] = (const char*)Bw + (size_t)(nt * 256 + a * 64 + rloc) * (HDIM * 2) + kofs + c16;
  }

  f32x4 acc[8][4] = {};
  gemm_core8(ga, gb, sm, KB / 128, tid, acc);

  const int l = tid & 63, w = tid >> 6;
  const int lr = l & 15, quad = l >> 4;
  const int wm = w >> 2, wn = w & 3;
#pragma unroll
  for (int i = 0; i < 8; ++i) {
#pragma unroll
    for (int r = 0; r < 4; ++r) {
      const int rowe = mt * 256 + wm * 128 + i * 16 + quad * 4 + r;
      if (rowe >= cnt) continue;
      const int rg = off + rowe;
      const int tok = row_token[rg];
      const float wt = row_w[rg];
#pragma unroll
      for (int j = 0; j < 4; ++j) {
        const int d = nt * 256 + wn * 64 + j * 16 + lr;
        const float base = (kc == 0) ? bb[d] : 0.f;  // bias once per output
        atomicAdd(&out[(size_t)tok * DDIM + d], wt * (acc[i][j][r] + base));
      }
    }
  }
}

// ---------------------------------------------------------------------------
extern "C" void kernel_launch(void* const* d_in, const int* in_sizes, int n_in,
                              void* d_out, int out_size, void* d_ws, size_t ws_size,
                              hipStream_t stream) {
  (void)in_sizes; (void)n_in; (void)out_size; (void)ws_size;
  const float* x    = (const float*)d_in[0];
  const float* Wg   = (const float*)d_in[1];
  const float* bg   = (const float*)d_in[2];
  const float* bias = (const float*)d_in[3];
  const float* W1   = (const float*)d_in[4];
  const float* b1   = (const float*)d_in[5];
  const float* W2   = (const float*)d_in[6];
  const float* b2   = (const float*)d_in[7];
  const float* Ws1  = (const float*)d_in[8];
  const float* bs1  = (const float*)d_in[9];
  const float* Ws2  = (const float*)d_in[10];
  const float* bs2  = (const float*)d_in[11];
  float* out = (float*)d_out;

  // workspace carve-out (~200 MB)
  char* ws = (char*)d_ws;
  size_t cur = 0;
  auto take = [&](size_t b) -> void* {
    void* p = ws + cur;
    cur += (b + 255) & ~(size_t)255;
    return p;
  };
  int* counts    = (int*)take(NEXP * 4);
  int* offsets   = (int*)take((NEXP + 1) * 4);
  int* topk_idx  = (int*)take(NTOK * 2 * 4);
  float* topk_w  = (float*)take(NTOK * 2 * 4);
  int* slot      = (int*)take(NTOK * 2 * 4);
  int* row_token = (int*)take(NROWS * 4);
  float* row_w   = (float*)take(NROWS * 4);
  __hip_bfloat16* xbf   = (__hip_bfloat16*)take((size_t)NTOK * DDIM * 2);        //  4 MB
  __hip_bfloat16* W1bf  = (__hip_bfloat16*)take((size_t)NEXP * HDIM * DDIM * 2); // 67 MB
  __hip_bfloat16* W2bf  = (__hip_bfloat16*)take((size_t)NEXP * DDIM * HDIM * 2); // 67 MB
  __hip_bfloat16* Ws1bf = (__hip_bfloat16*)take((size_t)HDIM * DDIM * 2);        //  8 MB
  __hip_bfloat16* Ws2bf = (__hip_bfloat16*)take((size_t)DDIM * HDIM * 2);        //  8 MB
  __hip_bfloat16* h1    = (__hip_bfloat16*)take((size_t)(NROWS + 64) * HDIM * 2);// 51 MB

  // f32 -> bf16 conversions (all sizes divisible by 2048)
  cvt_bf16<<<(NTOK * DDIM) / 2048, 256, 0, stream>>>(x, xbf);
  cvt_bf16<<<(NEXP * HDIM * DDIM) / 2048, 256, 0, stream>>>(W1, W1bf);
  cvt_bf16<<<(NEXP * DDIM * HDIM) / 2048, 256, 0, stream>>>(W2, W2bf);
  cvt_bf16<<<(HDIM * DDIM) / 2048, 256, 0, stream>>>(Ws1, Ws1bf);
  cvt_bf16<<<(DDIM * HDIM) / 2048, 256, 0, stream>>>(Ws2, Ws2bf);

  moe_zero_misc<<<1, 64, 0, stream>>>(counts);
  moe_zero_out<<<(NTOK * DDIM) / 256, 256, 0, stream>>>(out);
  moe_gate<<<NTOK, 64, 0, stream>>>(x, Wg, bg, bias, counts, topk_idx, topk_w, slot);
  moe_scan<<<1, 1, 0, stream>>>(counts, offsets);
  moe_scatter<<<NTOK / 256, 256, 0, stream>>>(topk_idx, topk_w, slot, offsets, row_token, row_w);

  dim3 g1(HDIM / 256, NTOK / 256, NEXP + 1);  // (16, 8, 9), early-exit past counts
  moe_gemm1<<<g1, 512, 0, stream>>>(xbf, W1bf, b1, Ws1bf, bs1, counts, offsets, row_token, h1);

  dim3 g2(KSPLIT2 * (DDIM / 256), NTOK / 256, NEXP + 1);  // (8, 8, 9), split-K
  moe_gemm2<<<g2, 512, 0, stream>>>(h1, W2bf, b2, Ws2bf, bs2, counts, offsets, row_token, row_w, out);
}

// Round 6
// 362.497 us; speedup vs baseline: 1.2205x; 1.1437x over previous
//
#include <hip/hip_runtime.h>
#include <hip/hip_bf16.h>
#include <math.h>

// Problem constants (B=2,S=1024 -> T=2048; D=1024; H=4096; E=8; top-2)
#define NTOK 2048
#define DDIM 1024
#define HDIM 4096
#define NEXP 8
#define NROWS (3 * NTOK)
#define KSPLIT2 2

typedef __bf16 bf16x8 __attribute__((ext_vector_type(8)));
typedef float f32x4 __attribute__((ext_vector_type(4)));
typedef __attribute__((address_space(1))) char as1_char;
typedef __attribute__((address_space(3))) char as3_char;

__device__ __forceinline__ void async16(const void* g, void* l) {
  __builtin_amdgcn_global_load_lds((as1_char*)g, (as3_char*)l, 16, 0, 0);
}

// Branch-free erf (A-S 7.1.26) -> exact-form gelu.
__device__ __forceinline__ float gelu_fast(float v) {
  const float x = v * 0.70710678118654752f;
  const float ax = fabsf(x);
  const float t = __builtin_amdgcn_rcpf(1.0f + 0.3275911f * ax);
  float p = 1.061405429f;
  p = p * t - 1.453152027f;
  p = p * t + 1.421413741f;
  p = p * t - 0.284496736f;
  p = p * t + 0.254829592f;
  const float y = 1.0f - p * t * __expf(-ax * ax);
  const float erfv = copysignf(y, x);
  return 0.5f * v * (1.0f + erfv);
}

// ---------------------------------------------------------------------------
// Fused f32->bf16 conversion for ALL five tensors in ONE launch (replaces 5
// kernels; saves 4 launch gaps). Segment sizes are all multiples of 2048
// elems, so each 256-thread block (8 elems/thread) is segment-uniform.
// Also folds the counts[] zeroing (block 0).
// Block ranges: x 1024 | W1 16384 | W2 16384 | Ws1 2048 | Ws2 2048 = 37888.
// ---------------------------------------------------------------------------
__global__ void __launch_bounds__(256) cvt_all(
    const float* __restrict__ x, const float* __restrict__ W1,
    const float* __restrict__ W2, const float* __restrict__ Ws1,
    const float* __restrict__ Ws2, __hip_bfloat16* __restrict__ xbf,
    __hip_bfloat16* __restrict__ W1bf, __hip_bfloat16* __restrict__ W2bf,
    __hip_bfloat16* __restrict__ Ws1bf, __hip_bfloat16* __restrict__ Ws2bf,
    int* __restrict__ counts) {
  const int b = blockIdx.x;
  if (b == 0 && threadIdx.x < NEXP) counts[threadIdx.x] = 0;
  const float* src;
  __hip_bfloat16* dst;
  size_t base;
  if (b < 1024)        { src = x;   dst = xbf;   base = (size_t)b * 2048; }
  else if (b < 17408)  { src = W1;  dst = W1bf;  base = (size_t)(b - 1024) * 2048; }
  else if (b < 33792)  { src = W2;  dst = W2bf;  base = (size_t)(b - 17408) * 2048; }
  else if (b < 35840)  { src = Ws1; dst = Ws1bf; base = (size_t)(b - 33792) * 2048; }
  else                 { src = Ws2; dst = Ws2bf; base = (size_t)(b - 35840) * 2048; }
  const size_t i = base + (size_t)threadIdx.x * 8;
  const float4 a = *(const float4*)(src + i);
  const float4 c = *(const float4*)(src + i + 4);
  union { __hip_bfloat16 h[8]; uint4 u; } p;
  p.h[0] = __float2bfloat16(a.x); p.h[1] = __float2bfloat16(a.y);
  p.h[2] = __float2bfloat16(a.z); p.h[3] = __float2bfloat16(a.w);
  p.h[4] = __float2bfloat16(c.x); p.h[5] = __float2bfloat16(c.y);
  p.h[6] = __float2bfloat16(c.z); p.h[7] = __float2bfloat16(c.w);
  *(uint4*)(dst + i) = p.u;
}

__global__ void moe_zero_out(float* __restrict__ a) {
  a[(size_t)blockIdx.x * 256 + threadIdx.x] = 0.f;
}

// ---------------------------------------------------------------------------
// Round-10 core: BM=256 x BN=128 tile, 4 waves (2M x 2N), PER-WAVE 128x64
// output (8x4 frags of 16x16x32 bf16; acc 128 VGPR).
// Post-mortem r5: the 8-phase port drained vmcnt(0) per K-tile (T4 violated)
// -> 190us. Rounds 2/3 fixed the invariant: ~595 cyc per barrier-pair for
// 16 MFMA/wave regardless of shape = ~300 cyc fixed overhead per pair. This
// core amortizes that pair over 32 MFMA + 12 b128 reads per wave (2x), and
// keeps the PROVEN round-2 pipeline: 3 LDS buffers, depth-2 prefetch,
// counted vmcnt (never drains in main loop).
// LDS/buf: A [256 x 64B] 16KB + B [128 x 64B] 8KB = 24KB; x3 = 72KB
// -> 2 blocks/CU (144KB), 8 waves/CU. VGPR ~200 -> 2 waves/SIMD OK.
// Staging per wave per K-tile: 4 A-DMAs (rows w*64..+64) + 2 B-DMAs
// (rows w*32..+32); depth-2 -> 12 outstanding after issuing kt+2 ->
// vmcnt(12) waits stage(kt) only.
// Swizzle (round-2-verified, conflicts==0): store 16B chunk c of row r at
// slot c^((r>>1)&3) via pre-swizzled global source (linear LDS dest, same
// 64B line); read slot quad^((lr>>1)&3).
// Schedule correctness: stage(i+2) overwrites buf (i-1)%3, whose readers all
// passed the trailing barrier of iter i-1; per-wave counted vmcnt before the
// leading barrier guarantees own stage(i) DMAs landed; barrier publishes.
// ---------------------------------------------------------------------------
__device__ __forceinline__ void gemm_core(const char* const gA[4], const char* const gB[2],
                                          char* sm, int Kbytes, int tid,
                                          f32x4 acc[8][4]) {
  const int w = tid >> 6, l = tid & 63;
  const int lr = l & 15, quad = l >> 4;
  const int wm = w >> 1, wn = w & 1;
  const int slot = (quad ^ ((lr >> 1) & 3)) * 16;     // bank-free read slot
  const int abase = (wm * 128 + lr) * 64 + slot;      // A frag i: +i*1024
  const int bbase = 16384 + (wn * 64 + lr) * 64 + slot;  // B frag j: +j*1024
  const int niter = Kbytes >> 6;

  auto stage = [&](int it, int buf) {
    char* base = sm + buf * 24576;
    const int kb = it * 64;
#pragma unroll
    for (int q = 0; q < 4; ++q) async16(gA[q] + kb, base + w * 4096 + q * 1024);
#pragma unroll
    for (int q = 0; q < 2; ++q) async16(gB[q] + kb, base + 16384 + w * 2048 + q * 1024);
  };

  stage(0, 0);
  stage(1, 1);
  int cur = 0, nxt = 2;
  for (int i = 0; i < niter; ++i) {
    if (i + 2 < niter) {
      stage(i + 2, nxt);                      // 12 DMAs outstanding (own)
      __builtin_amdgcn_s_waitcnt(0x0F7C);     // vmcnt(12): wait stage(i) only
    } else if (i + 1 < niter) {
      __builtin_amdgcn_s_waitcnt(0x0F76);     // vmcnt(6): stage(i+1) in flight
    } else {
      __builtin_amdgcn_s_waitcnt(0x0F70);     // vmcnt(0): last tile
    }
    __builtin_amdgcn_s_barrier();             // raw: prefetch stays in flight
    const char* rb = sm + cur * 24576;
    bf16x8 av[8], bv[4];
#pragma unroll
    for (int i2 = 0; i2 < 8; ++i2) av[i2] = *(const bf16x8*)(rb + abase + i2 * 1024);
#pragma unroll
    for (int j = 0; j < 4; ++j) bv[j] = *(const bf16x8*)(rb + bbase + j * 1024);
#pragma unroll
    for (int i2 = 0; i2 < 8; ++i2)
#pragma unroll
      for (int j = 0; j < 4; ++j)
        acc[i2][j] = __builtin_amdgcn_mfma_f32_16x16x32_bf16(av[i2], bv[j], acc[i2][j], 0, 0, 0);
    __builtin_amdgcn_s_barrier();             // all reads of buf[cur] done
    cur = (cur == 2) ? 0 : cur + 1;
    nxt = (nxt == 2) ? 0 : nxt + 1;
  }
}

// lane l stages chunk ((l&3)^((l>>3)&3)) of row (l>>2) in each 16-row DMA:
// places chunk c of row r at slot c^((r>>1)&3) with a LINEAR LDS dest.
__device__ __forceinline__ int stage_colb(int l) {
  return (((l & 3) ^ ((l >> 3) & 3)) * 16);
}

// ---------------------------------------------------------------------------
// Gating: one wave per token. Top-2, lax.top_k tie-break (lowest index).
// ---------------------------------------------------------------------------
__global__ void __launch_bounds__(64) moe_gate(
    const float* __restrict__ x, const float* __restrict__ Wg,
    const float* __restrict__ bg, const float* __restrict__ bias,
    int* __restrict__ counts, int* __restrict__ topk_idx,
    float* __restrict__ topk_w, int* __restrict__ slot) {
  const int t = blockIdx.x, lane = threadIdx.x;
  float xv[16];
#pragma unroll
  for (int q = 0; q < 16; ++q) xv[q] = x[(size_t)t * DDIM + q * 64 + lane];
  float sc[NEXP];
#pragma unroll
  for (int e = 0; e < NEXP; ++e) {
    float s = 0.f;
#pragma unroll
    for (int q = 0; q < 16; ++q) s += xv[q] * Wg[(size_t)e * DDIM + q * 64 + lane];
#pragma unroll
    for (int o = 32; o > 0; o >>= 1) s += __shfl_xor(s, o, 64);
    sc[e] = 1.0f / (1.0f + expf(-(s + bg[e] + bias[e])));
  }
  if (lane == 0) {
    int k0 = 0;
    for (int e = 1; e < NEXP; ++e)
      if (sc[e] > sc[k0]) k0 = e;
    int k1 = (k0 == 0) ? 1 : 0;
    for (int e = 0; e < NEXP; ++e) {
      if (e == k0) continue;
      if (sc[e] > sc[k1]) k1 = e;
    }
    topk_idx[t * 2 + 0] = k0;
    topk_idx[t * 2 + 1] = k1;
    topk_w[t * 2 + 0] = sc[k0];
    topk_w[t * 2 + 1] = sc[k1];
    slot[t * 2 + 0] = atomicAdd(&counts[k0], 1);
    slot[t * 2 + 1] = atomicAdd(&counts[k1], 1);
  }
}

__global__ void moe_scan(const int* __restrict__ counts, int* __restrict__ offsets) {
  if (threadIdx.x == 0) {
    int s = 0;
    for (int e = 0; e < NEXP; ++e) { offsets[e] = s; s += counts[e]; }
    offsets[NEXP] = s;
  }
}

__global__ void moe_scatter(const int* __restrict__ topk_idx, const float* __restrict__ topk_w,
                            const int* __restrict__ slot, const int* __restrict__ offsets,
                            int* __restrict__ row_token, float* __restrict__ row_w) {
  const int t = blockIdx.x * blockDim.x + threadIdx.x;
  if (t >= NTOK) return;
#pragma unroll
  for (int k = 0; k < 2; ++k) {
    const int e = topk_idx[t * 2 + k];
    const int rg = offsets[e] + slot[t * 2 + k];
    row_token[rg] = t;
    row_w[rg] = topk_w[t * 2 + k];
  }
  row_token[2 * NTOK + t] = t;
  row_w[2 * NTOK + t] = 1.0f;
}

// ---------------------------------------------------------------------------
// Grouped GEMM1: h1[row,:] = gelu(xbf[token(row),:] @ W1bf[e]^T + b1[e])
// 256(M) x 128(N) tiles: grid (H/128=32, NTOK/256=8, E+1).
// ---------------------------------------------------------------------------
__global__ void __launch_bounds__(256, 2) moe_gemm1(
    const __hip_bfloat16* __restrict__ xbf, const __hip_bfloat16* __restrict__ W1bf,
    const float* __restrict__ b1, const __hip_bfloat16* __restrict__ Ws1bf,
    const float* __restrict__ bs1, const int* __restrict__ counts,
    const int* __restrict__ offsets, const int* __restrict__ row_token,
    __hip_bfloat16* __restrict__ h1) {
  __shared__ alignas(16) char sm[73728];
  const int e = blockIdx.z, mt = blockIdx.y, nt = blockIdx.x;
  const int cnt = (e < NEXP) ? counts[e] : NTOK;
  if (mt * 256 >= cnt) return;
  const int off = (e < NEXP) ? offsets[e] : 2 * NTOK;
  const __hip_bfloat16* Bw = (e < NEXP) ? (W1bf + (size_t)e * HDIM * DDIM) : Ws1bf;
  const float* bb = (e < NEXP) ? (b1 + e * HDIM) : bs1;

  const int tid = threadIdx.x;
  const int w = tid >> 6, l = tid & 63;
  const int rl = l >> 2;
  const int colb = stage_colb(l);

  // A (token-gathered): wave w rows mt*256 + w*64 + q*16 + rl, q=0..3
  const char* ga[4];
#pragma unroll
  for (int q = 0; q < 4; ++q) {
    const int r = mt * 256 + w * 64 + q * 16 + rl;
    const int c = (r < cnt) ? r : (cnt - 1);
    const int tok = row_token[off + c];
    ga[q] = (const char*)xbf + (size_t)tok * (DDIM * 2) + colb;
  }
  // B: wave w rows nt*128 + w*32 + q*16 + rl, q=0..1
  const char* gb[2];
#pragma unroll
  for (int q = 0; q < 2; ++q) {
    const int br = nt * 128 + w * 32 + q * 16 + rl;
    gb[q] = (const char*)Bw + (size_t)br * (DDIM * 2) + colb;
  }

  f32x4 acc[8][4] = {};
  gemm_core(ga, gb, sm, DDIM * 2, tid, acc);

  const int lr = l & 15, quad = l >> 4, wm = w >> 1, wn = w & 1;
#pragma unroll
  for (int i = 0; i < 8; ++i) {
#pragma unroll
    for (int r = 0; r < 4; ++r) {
      const int rowe = mt * 256 + wm * 128 + i * 16 + quad * 4 + r;
      if (rowe >= cnt) continue;  // don't stomp next expert's rows
      const size_t orow = (size_t)(off + rowe) * HDIM;
#pragma unroll
      for (int j = 0; j < 4; ++j) {
        const int h = nt * 128 + wn * 64 + j * 16 + lr;
        const float v = acc[i][j][r] + bb[h];
        h1[orow + h] = __float2bfloat16(gelu_fast(v));
      }
    }
  }
}

// ---------------------------------------------------------------------------
// Grouped GEMM2 with split-K: out[token,:] += w(row)*(h1[row,:] @ W2bf[e]^T)
// (+ w*b2[e] from K-chunk 0). 256(M) x 128(N) tiles.
// grid x = KSPLIT2 * (D/128) = 16; y = NTOK/256 = 8; z = E+1.
// ---------------------------------------------------------------------------
__global__ void __launch_bounds__(256, 2) moe_gemm2(
    const __hip_bfloat16* __restrict__ h1, const __hip_bfloat16* __restrict__ W2bf,
    const float* __restrict__ b2, const __hip_bfloat16* __restrict__ Ws2bf,
    const float* __restrict__ bs2, const int* __restrict__ counts,
    const int* __restrict__ offsets, const int* __restrict__ row_token,
    const float* __restrict__ row_w, float* __restrict__ out) {
  __shared__ alignas(16) char sm[73728];
  const int e = blockIdx.z, mt = blockIdx.y;
  const int nt = blockIdx.x & (DDIM / 128 - 1);
  const int kc = blockIdx.x >> 3;
  const int cnt = (e < NEXP) ? counts[e] : NTOK;
  if (mt * 256 >= cnt) return;
  const int off = (e < NEXP) ? offsets[e] : 2 * NTOK;
  const __hip_bfloat16* Bw = (e < NEXP) ? (W2bf + (size_t)e * DDIM * HDIM) : Ws2bf;
  const float* bb = (e < NEXP) ? (b2 + e * DDIM) : bs2;

  const int tid = threadIdx.x;
  const int w = tid >> 6, l = tid & 63;
  const int rl = l >> 2;
  const int colb = stage_colb(l);
  const int KB = (HDIM * 2) / KSPLIT2;   // 4096 bytes per chunk
  const size_t kofs = (size_t)kc * KB;

  // A rows contiguous in grouped h1; rows >= cnt read next group's (finite)
  // data, discarded at the store guard.
  const char* ga[4];
#pragma unroll
  for (int q = 0; q < 4; ++q) {
    const int ar = mt * 256 + w * 64 + q * 16 + rl;
    ga[q] = (const char*)h1 + (size_t)(off + ar) * (HDIM * 2) + kofs + colb;
  }
  const char* gb[2];
#pragma unroll
  for (int q = 0; q < 2; ++q) {
    const int br = nt * 128 + w * 32 + q * 16 + rl;
    gb[q] = (const char*)Bw + (size_t)br * (HDIM * 2) + kofs + colb;
  }

  f32x4 acc[8][4] = {};
  gemm_core(ga, gb, sm, KB, tid, acc);

  const int lr = l & 15, quad = l >> 4, wm = w >> 1, wn = w & 1;
#pragma unroll
  for (int i = 0; i < 8; ++i) {
#pragma unroll
    for (int r = 0; r < 4; ++r) {
      const int rowe = mt * 256 + wm * 128 + i * 16 + quad * 4 + r;
      if (rowe >= cnt) continue;
      const int rg = off + rowe;
      const int tok = row_token[rg];
      const float wt = row_w[rg];
#pragma unroll
      for (int j = 0; j < 4; ++j) {
        const int d = nt * 128 + wn * 64 + j * 16 + lr;
        const float base = (kc == 0) ? bb[d] : 0.f;
        atomicAdd(&out[(size_t)tok * DDIM + d], wt * (acc[i][j][r] + base));
      }
    }
  }
}

// ---------------------------------------------------------------------------
extern "C" void kernel_launch(void* const* d_in, const int* in_sizes, int n_in,
                              void* d_out, int out_size, void* d_ws, size_t ws_size,
                              hipStream_t stream) {
  (void)in_sizes; (void)n_in; (void)out_size; (void)ws_size;
  const float* x    = (const float*)d_in[0];
  const float* Wg   = (const float*)d_in[1];
  const float* bg   = (const float*)d_in[2];
  const float* bias = (const float*)d_in[3];
  const float* W1   = (const float*)d_in[4];
  const float* b1   = (const float*)d_in[5];
  const float* W2   = (const float*)d_in[6];
  const float* b2   = (const float*)d_in[7];
  const float* Ws1  = (const float*)d_in[8];
  const float* bs1  = (const float*)d_in[9];
  const float* Ws2  = (const float*)d_in[10];
  const float* bs2  = (const float*)d_in[11];
  float* out = (float*)d_out;

  char* ws = (char*)d_ws;
  size_t cur = 0;
  auto take = [&](size_t b) -> void* {
    void* p = ws + cur;
    cur += (b + 255) & ~(size_t)255;
    return p;
  };
  int* counts    = (int*)take(NEXP * 4);
  int* offsets   = (int*)take((NEXP + 1) * 4);
  int* topk_idx  = (int*)take(NTOK * 2 * 4);
  float* topk_w  = (float*)take(NTOK * 2 * 4);
  int* slot      = (int*)take(NTOK * 2 * 4);
  int* row_token = (int*)take(NROWS * 4);
  float* row_w   = (float*)take(NROWS * 4);
  __hip_bfloat16* xbf   = (__hip_bfloat16*)take((size_t)NTOK * DDIM * 2);
  __hip_bfloat16* W1bf  = (__hip_bfloat16*)take((size_t)NEXP * HDIM * DDIM * 2);
  __hip_bfloat16* W2bf  = (__hip_bfloat16*)take((size_t)NEXP * DDIM * HDIM * 2);
  __hip_bfloat16* Ws1bf = (__hip_bfloat16*)take((size_t)HDIM * DDIM * 2);
  __hip_bfloat16* Ws2bf = (__hip_bfloat16*)take((size_t)DDIM * HDIM * 2);
  __hip_bfloat16* h1    = (__hip_bfloat16*)take((size_t)(NROWS + 64) * HDIM * 2);

  // single fused f32->bf16 pass (x, W1, W2, Ws1, Ws2) + counts zeroing
  cvt_all<<<37888, 256, 0, stream>>>(x, W1, W2, Ws1, Ws2,
                                     xbf, W1bf, W2bf, Ws1bf, Ws2bf, counts);

  moe_zero_out<<<(NTOK * DDIM) / 256, 256, 0, stream>>>(out);
  moe_gate<<<NTOK, 64, 0, stream>>>(x, Wg, bg, bias, counts, topk_idx, topk_w, slot);
  moe_scan<<<1, 1, 0, stream>>>(counts, offsets);
  moe_scatter<<<NTOK / 256, 256, 0, stream>>>(topk_idx, topk_w, slot, offsets, row_token, row_w);

  dim3 g1(HDIM / 128, NTOK / 256, NEXP + 1);  // (32, 8, 9)
  moe_gemm1<<<g1, 256, 0, stream>>>(xbf, W1bf, b1, Ws1bf, bs1, counts, offsets, row_token, h1);

  dim3 g2(KSPLIT2 * (DDIM / 128), NTOK / 256, NEXP + 1);  // (16, 8, 9)
  moe_gemm2<<<g2, 256, 0, stream>>>(h1, W2bf, b2, Ws2bf, bs2, counts, offsets, row_token, row_w, out);
}